// Round 1
// baseline (276.799 us; speedup 1.0000x reference)
//
#include <hip/hip_runtime.h>
#include <hip/hip_bf16.h>
#include <stdint.h>

// ClusterAssignment: out[n,k] = q/(row-sum q), q = 1/(1+||x_n-c_k||^2), ALPHA=1
// N=65536, K=1024, D=512, fp32 in/out.
// Strategy: fp32 norms + bf16 MFMA cross-term (m97 128^2 structure),
// fused numerator epilogue, separate row-normalize pass. No atomics.

#define N_ROWS 65536
#define K_CL   1024
#define D_DIM  512

typedef __attribute__((ext_vector_type(8))) short short8;
typedef __attribute__((ext_vector_type(4))) float f32x4;

__device__ __forceinline__ ushort f2bf(float f) {
    union { float f; uint32_t u; } v; v.f = f;
    uint32_t u = v.u;
    u += 0x7fffu + ((u >> 16) & 1u);   // RNE (inputs are finite normals)
    return (ushort)(u >> 16);
}

__device__ __forceinline__ float waveReduceSum(float s) {
#pragma unroll
    for (int off = 32; off; off >>= 1) s += __shfl_down(s, off, 64);
    return s;
}

// ---- prep: fp32 -> bf16 + row sum-of-squares (one wave per row of 512) ----
__global__ void prep_rows(const float* __restrict__ X, ushort* __restrict__ Xbf,
                          float* __restrict__ sq) {
    const int row  = blockIdx.x * 4 + (threadIdx.x >> 6);
    const int lane = threadIdx.x & 63;
    const float4* src = (const float4*)(X + (size_t)row * D_DIM);
    float4 a = src[lane * 2];
    float4 b = src[lane * 2 + 1];
    float s = (a.x*a.x + a.y*a.y) + (a.z*a.z + a.w*a.w)
            + (b.x*b.x + b.y*b.y) + (b.z*b.z + b.w*b.w);
    uint4 o;
    o.x = (uint32_t)f2bf(a.x) | ((uint32_t)f2bf(a.y) << 16);
    o.y = (uint32_t)f2bf(a.z) | ((uint32_t)f2bf(a.w) << 16);
    o.z = (uint32_t)f2bf(b.x) | ((uint32_t)f2bf(b.y) << 16);
    o.w = (uint32_t)f2bf(b.z) | ((uint32_t)f2bf(b.w) << 16);
    *(uint4*)(Xbf + (size_t)row * D_DIM + lane * 8) = o;
    s = waveReduceSum(s);
    if (lane == 0) sq[row] = s;
}

// ---- GEMM + numerator epilogue: m97 structure, 128x128 tile, BK=32 ----
// C[n,k] = sum_d A[n,d]*B[k,d]  (both row-major "B^T" GEMM)
__global__ __launch_bounds__(256, 3) void gemm_numer(
    const ushort* __restrict__ A, const ushort* __restrict__ B,
    const float* __restrict__ xsq, const float* __restrict__ csq,
    float* __restrict__ out)
{
    __shared__ __align__(16) ushort smA[128 * 32];  // 8 KB
    __shared__ __align__(16) ushort smB[128 * 32];  // 8 KB

    const int nbn = K_CL / 128;                   // 8
    const int nwg = (N_ROWS / 128) * nbn;         // 4096, %8==0
    int bid = blockIdx.x;
    int swz = (bid & 7) * (nwg >> 3) + (bid >> 3);  // XCD-aware swizzle
    const int bm = swz / nbn, bn = swz % nbn;

    const int tid  = threadIdx.x;
    const int wid  = tid >> 6;
    const int lane = tid & 63;
    const int wm = wid >> 1, wn = wid & 1;        // 2x2 waves of 64x64
    const int l4 = lane >> 4, l16 = lane & 15;

    const ushort* gA = A + (size_t)bm * 128 * D_DIM;
    const ushort* gB = B + (size_t)bn * 128 * D_DIM;

    // staging: each wave issues 2x16B-per-lane loads per operand (1KB chunks)
    const int c0   = wid * 2;
    const int srow = lane >> 2;        // 16 rows per 1KB chunk
    const int scol = (lane & 3) * 8;   // 4 lanes x 8 bf16 per 32-col row

    f32x4 acc[4][4] = {};

    for (int kt = 0; kt < D_DIM; kt += 32) {
#pragma unroll
        for (int i = 0; i < 2; ++i) {
            const int c = c0 + i;
            const ushort* sA = gA + (size_t)(c * 16 + srow) * D_DIM + kt + scol;
            const ushort* sB = gB + (size_t)(c * 16 + srow) * D_DIM + kt + scol;
            __builtin_amdgcn_global_load_lds(
                (const __attribute__((address_space(1))) void*)sA,
                (__attribute__((address_space(3))) void*)(smA + c * 512), 16, 0, 0);
            __builtin_amdgcn_global_load_lds(
                (const __attribute__((address_space(1))) void*)sB,
                (__attribute__((address_space(3))) void*)(smB + c * 512), 16, 0, 0);
        }
        __syncthreads();   // compiler drains vmcnt before barrier

        short8 af[4], bf[4];
#pragma unroll
        for (int m = 0; m < 4; ++m)
            af[m] = *(const short8*)(smA + (wm * 64 + m * 16 + l16) * 32 + l4 * 8);
#pragma unroll
        for (int n = 0; n < 4; ++n)
            bf[n] = *(const short8*)(smB + (wn * 64 + n * 16 + l16) * 32 + l4 * 8);
#pragma unroll
        for (int m = 0; m < 4; ++m)
#pragma unroll
            for (int n = 0; n < 4; ++n)
                acc[m][n] = __builtin_amdgcn_mfma_f32_16x16x32_bf16(
                    af[m], bf[n], acc[m][n], 0, 0, 0);
        __syncthreads();
    }

    // epilogue: numerator = 1/(1 + max(xsq - 2*cross + csq, 0))
    const int orow0 = bm * 128 + wm * 64;
    const int ocol0 = bn * 128 + wn * 64;
    float xs[4][4];
#pragma unroll
    for (int m = 0; m < 4; ++m)
#pragma unroll
        for (int r = 0; r < 4; ++r)
            xs[m][r] = xsq[orow0 + m * 16 + l4 * 4 + r];
#pragma unroll
    for (int n = 0; n < 4; ++n) {
        const int col = ocol0 + n * 16 + l16;
        const float cs = csq[col];
#pragma unroll
        for (int m = 0; m < 4; ++m) {
#pragma unroll
            for (int r = 0; r < 4; ++r) {
                const int row = orow0 + m * 16 + l4 * 4 + r;
                float ns = xs[m][r] - 2.0f * acc[m][n][r] + cs;
                ns = fmaxf(ns, 0.0f);
                out[(size_t)row * K_CL + col] = 1.0f / (1.0f + ns);
            }
        }
    }
}

// ---- in-place row normalize: one wave per row of K=1024 ----
__global__ void normalize_rows(float* __restrict__ out) {
    const int row  = blockIdx.x * 4 + (threadIdx.x >> 6);
    const int lane = threadIdx.x & 63;
    float4* p = (float4*)(out + (size_t)row * K_CL);
    float4 v[4];
    float s = 0.f;
#pragma unroll
    for (int i = 0; i < 4; ++i) {
        v[i] = p[i * 64 + lane];
        s += (v[i].x + v[i].y) + (v[i].z + v[i].w);
    }
    s = waveReduceSum(s);
    s = __shfl(s, 0, 64);
    const float inv = 1.0f / s;
#pragma unroll
    for (int i = 0; i < 4; ++i) {
        float4 w = v[i];
        w.x *= inv; w.y *= inv; w.z *= inv; w.w *= inv;
        p[i * 64 + lane] = w;
    }
}

extern "C" void kernel_launch(void* const* d_in, const int* in_sizes, int n_in,
                              void* d_out, int out_size, void* d_ws, size_t ws_size,
                              hipStream_t stream) {
    const float* batch   = (const float*)d_in[0];
    const float* centers = (const float*)d_in[1];
    float* out = (float*)d_out;

    char* ws = (char*)d_ws;
    ushort* Abf = (ushort*)ws;                                          // 64 MB
    ushort* Bbf = (ushort*)(ws + (size_t)N_ROWS * D_DIM * 2);          // 1 MB
    float*  xsq = (float*)(ws + (size_t)N_ROWS * D_DIM * 2
                              + (size_t)K_CL * D_DIM * 2);             // 256 KB
    float*  csq = xsq + N_ROWS;                                         // 4 KB
    (void)in_sizes; (void)n_in; (void)out_size; (void)ws_size;

    prep_rows<<<K_CL / 4,  256, 0, stream>>>(centers, Bbf, csq);
    prep_rows<<<N_ROWS / 4, 256, 0, stream>>>(batch, Abf, xsq);
    gemm_numer<<<(N_ROWS / 128) * (K_CL / 128), 256, 0, stream>>>(Abf, Bbf, xsq, csq, out);
    normalize_rows<<<N_ROWS / 4, 256, 0, stream>>>(out);
}

// Round 2
// 207.175 us; speedup vs baseline: 1.3361x; 1.3361x over previous
//
#include <hip/hip_runtime.h>
#include <hip/hip_bf16.h>
#include <stdint.h>

// ClusterAssignment: out[n,k] = q/(row-sum q), q = 1/(1+||x_n-c_k||^2), ALPHA=1
// N=65536, K=1024, D=512, fp32 in/out.
// R2: full-K blocks (64 rows x 1024 cols) -> normalize fused into GEMM
// epilogue (kills the 85us/512MB normalize pass). BK=64 + XOR-swizzled LDS
// (T2; rule #21: linear gload_lds dest, inverse-swizzled source, swizzled
// read) kills the 8.4M bank conflicts.

#define N_ROWS 65536
#define K_CL   1024
#define D_DIM  512
#define BM     64
#define BK     64

typedef __attribute__((ext_vector_type(8))) short short8;
typedef __attribute__((ext_vector_type(4))) float f32x4;

__device__ __forceinline__ ushort f2bf(float f) {
    union { float f; uint32_t u; } v; v.f = f;
    uint32_t u = v.u;
    u += 0x7fffu + ((u >> 16) & 1u);   // RNE (inputs are finite normals)
    return (ushort)(u >> 16);
}

__device__ __forceinline__ float waveReduceSum(float s) {
#pragma unroll
    for (int off = 32; off; off >>= 1) s += __shfl_down(s, off, 64);
    return s;
}

// ---- prep: fp32 -> bf16 + row sum-of-squares (one wave per row of 512) ----
__global__ void prep_rows(const float* __restrict__ X, ushort* __restrict__ Xbf,
                          float* __restrict__ sq) {
    const int row  = blockIdx.x * 4 + (threadIdx.x >> 6);
    const int lane = threadIdx.x & 63;
    const float4* src = (const float4*)(X + (size_t)row * D_DIM);
    float4 a = src[lane * 2];
    float4 b = src[lane * 2 + 1];
    float s = (a.x*a.x + a.y*a.y) + (a.z*a.z + a.w*a.w)
            + (b.x*b.x + b.y*b.y) + (b.z*b.z + b.w*b.w);
    uint4 o;
    o.x = (uint32_t)f2bf(a.x) | ((uint32_t)f2bf(a.y) << 16);
    o.y = (uint32_t)f2bf(a.z) | ((uint32_t)f2bf(a.w) << 16);
    o.z = (uint32_t)f2bf(b.x) | ((uint32_t)f2bf(b.y) << 16);
    o.w = (uint32_t)f2bf(b.z) | ((uint32_t)f2bf(b.w) << 16);
    *(uint4*)(Xbf + (size_t)row * D_DIM + lane * 8) = o;
    s = waveReduceSum(s);
    if (lane == 0) sq[row] = s;
}

// ---- fused GEMM + numerator + row-normalize ----
// Block: 64 rows x full K=1024. 8 waves; wave w owns cols [w*128, w*128+128).
// C[n,k] = sum_d A[n,d]*B[k,d]; numer = 1/(1+max(xsq-2C+csq,0));
// out = numer / row_sum(numer).
__global__ __launch_bounds__(512, 2) void gemm_fused(
    const ushort* __restrict__ A, const ushort* __restrict__ B,
    const float* __restrict__ xsq, const float* __restrict__ csq,
    float* __restrict__ out)
{
    // [row][BK] bf16, 128 B rows; slot s (16B) of row r holds global slot s^(r&7)
    __shared__ __align__(16) ushort smA[BM * BK];       // 8 KB
    __shared__ __align__(16) ushort smB[K_CL * BK];     // 128 KB

    const int tid  = threadIdx.x;
    const int w    = tid >> 6;
    const int lane = tid & 63;
    const int l4 = lane >> 4, l16 = lane & 15;
    const int rbase = blockIdx.x * BM;

    // staging: thread t writes LDS bytes [t*16, t*16+16) of each 8KB chunk
    // (linear dest); source slot is XOR-swizzled so reads can swizzle.
    const int srow  = tid >> 3;                 // 0..63 within chunk
    const int sslot = (tid & 7) ^ (srow & 7);   // inverse(=same) swizzle
    const ushort* gA = A + (size_t)(rbase + srow) * D_DIM + sslot * 8;
    const ushort* gB = B + (size_t)srow * D_DIM + sslot * 8;
    ushort* ldsA = smA + w * 512;               // wave-uniform base (bytes w*1024)

    f32x4 acc[4][8] = {};
    const int sw = (l16 & 7) << 4;              // read-side byte swizzle

    for (int kt = 0; kt < D_DIM; kt += BK) {
        __builtin_amdgcn_global_load_lds(
            (const __attribute__((address_space(1))) void*)(gA + kt),
            (__attribute__((address_space(3))) void*)ldsA, 16, 0, 0);
#pragma unroll
        for (int c = 0; c < 16; ++c) {
            const ushort* src = gB + (size_t)c * 64 * D_DIM + kt;  // rows c*64..+63
            __builtin_amdgcn_global_load_lds(
                (const __attribute__((address_space(1))) void*)src,
                (__attribute__((address_space(3))) void*)(smB + c * 4096 + w * 512),
                16, 0, 0);
        }
        __syncthreads();   // drains vmcnt before barrier

#pragma unroll
        for (int kk = 0; kk < 2; ++kk) {
            const int cb = kk * 64;   // byte col base within 128 B row
            short8 af[4], bf[8];
#pragma unroll
            for (int m = 0; m < 4; ++m) {
                const int row = m * 16 + l16;
                af[m] = *(const short8*)((const char*)smA
                        + row * 128 + ((cb + l4 * 16) ^ sw));
            }
#pragma unroll
            for (int n = 0; n < 8; ++n) {
                const int row = w * 128 + n * 16 + l16;
                bf[n] = *(const short8*)((const char*)smB
                        + row * 128 + ((cb + l4 * 16) ^ sw));
            }
#pragma unroll
            for (int m = 0; m < 4; ++m)
#pragma unroll
                for (int n = 0; n < 8; ++n)
                    acc[m][n] = __builtin_amdgcn_mfma_f32_16x16x32_bf16(
                        af[m], bf[n], acc[m][n], 0, 0, 0);
        }
        __syncthreads();
    }

    // ---- epilogue: numerator + fused row-normalize ----
    // C/D layout: col = l16, row = l4*4 + reg (per 16x16 frag)
    float xs[4][4];
#pragma unroll
    for (int m = 0; m < 4; ++m)
#pragma unroll
        for (int r = 0; r < 4; ++r)
            xs[m][r] = xsq[rbase + m * 16 + l4 * 4 + r];

    float s[4][4] = {{0.f}};
#pragma unroll
    for (int n = 0; n < 8; ++n) {
        const float cs = csq[w * 128 + n * 16 + l16];
#pragma unroll
        for (int m = 0; m < 4; ++m)
#pragma unroll
            for (int r = 0; r < 4; ++r) {
                float ns = fmaxf(xs[m][r] - 2.0f * acc[m][n][r] + cs, 0.0f);
                float p = 1.0f / (1.0f + ns);
                acc[m][n][r] = p;
                s[m][r] += p;
            }
    }
    // reduce across the 16 col-lanes of each 16-lane group
#pragma unroll
    for (int m = 0; m < 4; ++m)
#pragma unroll
        for (int r = 0; r < 4; ++r) {
            float v = s[m][r];
            v += __shfl_xor(v, 1, 64);
            v += __shfl_xor(v, 2, 64);
            v += __shfl_xor(v, 4, 64);
            v += __shfl_xor(v, 8, 64);
            s[m][r] = v;
        }
    // cross-wave reduce via LDS (alias smA; loop's trailing barrier protects)
    float* smRS  = (float*)smA;         // [8 waves][64 rows]
    float* smInv = (float*)smA + 512;   // [64]
    if (l16 == 0) {
#pragma unroll
        for (int m = 0; m < 4; ++m)
#pragma unroll
            for (int r = 0; r < 4; ++r)
                smRS[w * 64 + m * 16 + l4 * 4 + r] = s[m][r];
    }
    __syncthreads();
    if (tid < 64) {
        float t = 0.f;
#pragma unroll
        for (int j = 0; j < 8; ++j) t += smRS[j * 64 + tid];
        smInv[tid] = 1.0f / t;
    }
    __syncthreads();

    float inv[4][4];
#pragma unroll
    for (int m = 0; m < 4; ++m)
#pragma unroll
        for (int r = 0; r < 4; ++r)
            inv[m][r] = smInv[m * 16 + l4 * 4 + r];   // broadcast read

#pragma unroll
    for (int m = 0; m < 4; ++m)
#pragma unroll
        for (int n = 0; n < 8; ++n) {
            const int col = w * 128 + n * 16 + l16;
#pragma unroll
            for (int r = 0; r < 4; ++r) {
                const int row = rbase + m * 16 + l4 * 4 + r;
                out[(size_t)row * K_CL + col] = acc[m][n][r] * inv[m][r];
            }
        }
}

extern "C" void kernel_launch(void* const* d_in, const int* in_sizes, int n_in,
                              void* d_out, int out_size, void* d_ws, size_t ws_size,
                              hipStream_t stream) {
    const float* batch   = (const float*)d_in[0];
    const float* centers = (const float*)d_in[1];
    float* out = (float*)d_out;

    char* ws = (char*)d_ws;
    ushort* Abf = (ushort*)ws;                                          // 64 MB
    ushort* Bbf = (ushort*)(ws + (size_t)N_ROWS * D_DIM * 2);          // 1 MB
    float*  xsq = (float*)(ws + (size_t)N_ROWS * D_DIM * 2
                              + (size_t)K_CL * D_DIM * 2);             // 256 KB
    float*  csq = xsq + N_ROWS;                                         // 4 KB
    (void)in_sizes; (void)n_in; (void)out_size; (void)ws_size;

    prep_rows<<<K_CL / 4,   256, 0, stream>>>(centers, Bbf, csq);
    prep_rows<<<N_ROWS / 4, 256, 0, stream>>>(batch, Abf, xsq);
    gemm_fused<<<N_ROWS / BM, 512, 0, stream>>>(Abf, Bbf, xsq, csq, out);
}